// Round 1
// baseline (1488.231 us; speedup 1.0000x reference)
//
#include <hip/hip_runtime.h>
#include <stdint.h>

// MoE top-1 dispatch: router (fp32) + grouped bf16-MFMA GEMM over expert-sorted tokens.
// ws layout (bytes):
//   0          : xs   bf16 [N][1024]  expert-sorted x            (64 MB)
//   67108864   : h    bf16 [N][2048]  relu(x@W1+b1), sorted      (128 MB)
//   201326592  : W1t  bf16 [8][2048][1024]                       (32 MB)
//   234881024  : W2t  bf16 [8][1024][2048]                       (32 MB)
//   268435456  : aux  int[4096]: cnt[0..7] cursor[8..15] ntiles[16] offs[24..32]
//                tile_e[128..] tile_r0[512..] tile_r1[896..]     (16 KB, memset 0 each launch)
//   268451840  : routes     int[N]
//   268582912  : pos_of_tok int[N]
//   268713984  : tok_of_pos int[N]   -> total 268,845,056 B

#define NTOK   32768
#define DIN    1024
#define DH     2048
#define DOUT   1024
#define NEXP   8

typedef unsigned short u16;
typedef __bf16 bf16x8 __attribute__((ext_vector_type(8)));
typedef float  f32x4  __attribute__((ext_vector_type(4)));
typedef const __attribute__((address_space(1))) void gvoid_t;
typedef __attribute__((address_space(3))) void svoid_t;

__device__ __forceinline__ u16 f2bf(float f) {
  union { float f; uint32_t u; } v; v.f = f;
  return (u16)((v.u + 0x7FFFu + ((v.u >> 16) & 1u)) >> 16);  // RNE, no NaN in data
}

// ---------------- router: logits, softmax, argmax, counts ----------------
__global__ __launch_bounds__(256) void k_router(
    const float* __restrict__ x, const float* __restrict__ Wr,
    const float* __restrict__ br, float* __restrict__ probs,
    int* __restrict__ routes, int* __restrict__ aux)
{
  __shared__ float wr_s[NEXP * DIN];  // transposed Wr: [e][k]
  int tid = threadIdx.x;
  for (int idx = tid; idx < DIN * NEXP / 4; idx += 256) {
    float4 v = ((const float4*)Wr)[idx];
    int k = idx >> 1, r = (idx & 1) * 4;
    wr_s[(r + 0) * DIN + k] = v.x;
    wr_s[(r + 1) * DIN + k] = v.y;
    wr_s[(r + 2) * DIN + k] = v.z;
    wr_s[(r + 3) * DIN + k] = v.w;
  }
  __syncthreads();
  int lane = tid & 63, wv = tid >> 6;
  int t = blockIdx.x * 4 + wv;
  const float* xr = x + (size_t)t * DIN;
  float acc[NEXP];
  #pragma unroll
  for (int e = 0; e < NEXP; ++e) acc[e] = 0.f;
  #pragma unroll
  for (int i = 0; i < 4; ++i) {
    int k = i * 256 + lane * 4;
    float4 xv = *(const float4*)(xr + k);
    #pragma unroll
    for (int e = 0; e < NEXP; ++e) {
      float4 w4 = *(const float4*)(wr_s + e * DIN + k);
      acc[e] += xv.x * w4.x + xv.y * w4.y + xv.z * w4.z + xv.w * w4.w;
    }
  }
  #pragma unroll
  for (int off = 32; off >= 1; off >>= 1) {
    #pragma unroll
    for (int e = 0; e < NEXP; ++e) acc[e] += __shfl_xor(acc[e], off, 64);
  }
  if (lane == 0) {
    float l[NEXP], m = -1e30f;
    #pragma unroll
    for (int e = 0; e < NEXP; ++e) { l[e] = acc[e] + br[e]; m = fmaxf(m, l[e]); }
    float p[NEXP], s = 0.f;
    #pragma unroll
    for (int e = 0; e < NEXP; ++e) { p[e] = expf(l[e] - m); s += p[e]; }
    float inv = 1.f / s;
    int am = 0; float best = l[0];
    #pragma unroll
    for (int e = 1; e < NEXP; ++e) if (l[e] > best) { best = l[e]; am = e; }
    #pragma unroll
    for (int e = 0; e < NEXP; ++e) probs[(size_t)t * NEXP + e] = p[e] * inv;
    routes[t] = am;
    atomicAdd(&aux[am], 1);
  }
}

// ---------------- prefix + tile map (1 block) ----------------
__global__ void k_prefix(int* __restrict__ aux, float* __restrict__ counts_out)
{
  if (threadIdx.x == 0) {
    int off = 0, nt = 0;
    for (int e = 0; e < NEXP; ++e) {
      int c = aux[e];
      counts_out[e] = (float)c;
      aux[24 + e] = off;
      int tiles = (c + 127) >> 7;
      for (int tt = 0; tt < tiles; ++tt) {
        aux[128 + nt] = e;
        aux[512 + nt] = off + tt * 128;
        aux[896 + nt] = off + c;
        ++nt;
      }
      off += c;
    }
    aux[16] = nt;
  }
}

// ---------------- slot assignment ----------------
__global__ __launch_bounds__(256) void k_assign(
    const int* __restrict__ routes, int* __restrict__ aux,
    int* __restrict__ pos_of_tok, int* __restrict__ tok_of_pos)
{
  int t = blockIdx.x * 256 + threadIdx.x;
  int e = routes[t];
  int p = aux[24 + e] + atomicAdd(&aux[8 + e], 1);
  pos_of_tok[t] = p;
  tok_of_pos[p] = t;
}

// ---------------- gather x into sorted order, fp32 -> bf16 ----------------
__global__ __launch_bounds__(256) void k_permute(
    const float* __restrict__ x, const int* __restrict__ pos_of_tok,
    u16* __restrict__ xs)
{
  int t = blockIdx.x * 2 + (threadIdx.x >> 7);
  int j = threadIdx.x & 127;
  int p = pos_of_tok[t];
  const float4* src = (const float4*)(x + (size_t)t * DIN);
  u16* dst = xs + (size_t)p * DIN;
  #pragma unroll
  for (int h = 0; h < 2; ++h) {
    float4 v = src[h * 128 + j];
    ushort4 o;
    o.x = f2bf(v.x); o.y = f2bf(v.y); o.z = f2bf(v.z); o.w = f2bf(v.w);
    *(ushort4*)(dst + (h * 128 + j) * 4) = o;
  }
}

// ---------------- weight transpose+convert: [E][K][Nn] f32 -> [E][Nn][K] bf16 ----------------
__global__ __launch_bounds__(256) void k_transpose(
    const float* __restrict__ src, u16* __restrict__ dst, int K, int Nn)
{
  __shared__ float tile[64][65];
  int e = blockIdx.z;
  int k0 = blockIdx.x * 64, n0 = blockIdx.y * 64;
  const float* s = src + ((size_t)e * K + k0) * Nn + n0;
  int r = threadIdx.x >> 6, c = threadIdx.x & 63;
  #pragma unroll
  for (int i = 0; i < 16; ++i)
    tile[r + i * 4][c] = s[(size_t)(r + i * 4) * Nn + c];
  __syncthreads();
  u16* d = dst + ((size_t)e * Nn + n0) * K + k0;
  #pragma unroll
  for (int i = 0; i < 16; ++i) {
    int nr = r + i * 4;
    d[(size_t)nr * K + c] = f2bf(tile[c][nr]);
  }
}

// ---------------- grouped GEMM, 128x256 tile, BK=64, 4 waves (each 128x64 out) ----------------
// MODE 0: H = relu(A@B^T + bias) -> bf16   MODE 1: out[tok] = A@B^T + bias -> f32 scatter
template<int MODE>
__global__ __launch_bounds__(256) void k_gemm(
    const u16* __restrict__ A, const u16* __restrict__ Bt,
    const float* __restrict__ bias, u16* __restrict__ Hout,
    float* __restrict__ Yout, const int* __restrict__ tok_of_pos,
    const int* __restrict__ aux, int K, int Nn)
{
  int bx = blockIdx.x;
  if (bx >= aux[16]) return;
  int e  = aux[128 + bx];
  int r0 = aux[512 + bx];
  int r1 = aux[896 + bx];
  int bn0 = blockIdx.y * 256;

  __shared__ __align__(16) u16 As[128 * 64];   // [row][k], rows 128B, slot-swizzled
  __shared__ __align__(16) u16 Bs[256 * 64];

  int tid = threadIdx.x;
  int lane = tid & 63, wv = tid >> 6;
  const u16* Be = Bt + (size_t)e * Nn * K;

  auto stage = [&](int kt) {
    int k0 = kt * 64;
    #pragma unroll
    for (int r = 0; r < 4; ++r) {              // A: 16 KB
      int L = (r * 256 + tid) * 16;
      int row = L >> 7;
      int sl = ((L >> 4) & 7) ^ (row & 7);     // pre-swizzle the global source
      int grow = r0 + row; grow = grow < NTOK ? grow : NTOK - 1;
      const char* ga = (const char*)(A + (size_t)grow * K + k0) + sl * 16;
      __builtin_amdgcn_global_load_lds((gvoid_t*)ga, (svoid_t*)((char*)As + L), 16, 0, 0);
    }
    #pragma unroll
    for (int r = 0; r < 8; ++r) {              // B: 32 KB
      int L = (r * 256 + tid) * 16;
      int row = L >> 7;
      int sl = ((L >> 4) & 7) ^ (row & 7);
      const char* gb = (const char*)(Be + (size_t)(bn0 + row) * K + k0) + sl * 16;
      __builtin_amdgcn_global_load_lds((gvoid_t*)gb, (svoid_t*)((char*)Bs + L), 16, 0, 0);
    }
  };

  f32x4 acc[8][4];
  #pragma unroll
  for (int i = 0; i < 8; ++i)
    #pragma unroll
    for (int j = 0; j < 4; ++j)
      acc[i][j] = (f32x4){0.f, 0.f, 0.f, 0.f};

  int KT = K >> 6;
  stage(0);
  for (int kt = 0; kt < KT; ++kt) {
    __syncthreads();
    const char* As_c = (const char*)As;
    const char* Bs_c = (const char*)Bs;
    #pragma unroll
    for (int kk = 0; kk < 2; ++kk) {
      int sw = ((kk * 4 + (lane >> 4)) ^ (lane & 7)) << 4;   // swizzled 16B slot
      bf16x8 a[8], b[4];
      #pragma unroll
      for (int f = 0; f < 8; ++f)
        a[f] = *(const bf16x8*)(As_c + (f * 16 + (lane & 15)) * 128 + sw);
      #pragma unroll
      for (int f = 0; f < 4; ++f)
        b[f] = *(const bf16x8*)(Bs_c + (size_t)(wv * 64 + f * 16 + (lane & 15)) * 128 + sw);
      #pragma unroll
      for (int i = 0; i < 8; ++i)
        #pragma unroll
        for (int j = 0; j < 4; ++j)
          acc[i][j] = __builtin_amdgcn_mfma_f32_16x16x32_bf16(a[i], b[j], acc[i][j], 0, 0, 0);
    }
    __syncthreads();
    if (kt + 1 < KT) stage(kt + 1);
  }

  const float* be = bias + (size_t)e * Nn;
  #pragma unroll
  for (int j = 0; j < 4; ++j) {
    int n = bn0 + wv * 64 + j * 16 + (lane & 15);
    float bv = be[n];
    #pragma unroll
    for (int i = 0; i < 8; ++i) {
      #pragma unroll
      for (int q = 0; q < 4; ++q) {
        int r = r0 + i * 16 + (lane >> 4) * 4 + q;   // C/D: col=lane&15, row=(lane>>4)*4+q [m89]
        if (r < r1) {
          float v = acc[i][j][q] + bv;
          if (MODE == 0) {
            v = fmaxf(v, 0.f);
            Hout[(size_t)r * Nn + n] = f2bf(v);
          } else {
            int tok = tok_of_pos[r];
            Yout[(size_t)tok * Nn + n] = v;
          }
        }
      }
    }
  }
}

extern "C" void kernel_launch(void* const* d_in, const int* in_sizes, int n_in,
                              void* d_out, int out_size, void* d_ws, size_t ws_size,
                              hipStream_t stream)
{
  const float* x  = (const float*)d_in[0];
  const float* Wr = (const float*)d_in[1];
  const float* br = (const float*)d_in[2];
  const float* W1 = (const float*)d_in[3];
  const float* b1 = (const float*)d_in[4];
  const float* W2 = (const float*)d_in[5];
  const float* b2 = (const float*)d_in[6];

  float* out    = (float*)d_out;                       // [N][1024]
  float* probs  = out + (size_t)NTOK * DOUT;           // [N][8]
  float* counts = probs + (size_t)NTOK * NEXP;         // [8]

  char* ws = (char*)d_ws;
  u16* xs          = (u16*)(ws);
  u16* h           = (u16*)(ws + 67108864);
  u16* W1t         = (u16*)(ws + 201326592);
  u16* W2t         = (u16*)(ws + 234881024);
  int* aux         = (int*)(ws + 268435456);
  int* routes      = (int*)(ws + 268451840);
  int* pos_of_tok  = (int*)(ws + 268582912);
  int* tok_of_pos  = (int*)(ws + 268713984);

  (void)hipMemsetAsync(aux, 0, 16384, stream);
  k_router<<<NTOK / 4, 256, 0, stream>>>(x, Wr, br, probs, routes, aux);
  k_transpose<<<dim3(DIN / 64, DH / 64, NEXP), 256, 0, stream>>>(W1, W1t, DIN, DH);
  k_transpose<<<dim3(DH / 64, DOUT / 64, NEXP), 256, 0, stream>>>(W2, W2t, DH, DOUT);
  k_prefix<<<1, 64, 0, stream>>>(aux, counts);
  k_assign<<<NTOK / 256, 256, 0, stream>>>(routes, aux, pos_of_tok, tok_of_pos);
  k_permute<<<NTOK / 2, 256, 0, stream>>>(x, pos_of_tok, xs);
  k_gemm<0><<<dim3(264, DH / 256), 256, 0, stream>>>(xs, W1t, b1, h, nullptr, nullptr, aux, DIN, DH);
  k_gemm<1><<<dim3(264, DOUT / 256), 256, 0, stream>>>(h, W2t, b2, nullptr, out, tok_of_pos, aux, DH, DOUT);
}

// Round 4
// 637.576 us; speedup vs baseline: 2.3342x; 2.3342x over previous
//
#include <hip/hip_runtime.h>
#include <stdint.h>

// MoE top-1: router (fp32) + grouped bf16-MFMA GEMM over expert-sorted tokens.
// R2 (resubmit x2 after container failures): m97-replica GEMM (128x128 tile, 4x4
// acc/wave, 3 blocks/CU) + ballot-based counting/assignment (64x fewer atomics).
// ws layout (bytes):
//   0          : xs   bf16 [N][1024]  expert-sorted x            (64 MB)
//   67108864   : h    bf16 [N][2048]  relu(x@W1+b1), sorted      (128 MB)
//   201326592  : W1t  bf16 [8][2048][1024]                       (32 MB)
//   234881024  : W2t  bf16 [8][1024][2048]                       (32 MB)
//   268435456  : aux  int[4096]: cnt[0..7] cursor[8..15] ntiles[16] offs[24..31]
//                tile_e[128..] tile_r0[512..] tile_r1[896..]     (16 KB, memset 0)
//   268451840  : routes     int[N]
//   268582912  : pos_of_tok int[N]
//   268713984  : tok_of_pos int[N]   -> total 268,845,056 B

#define NTOK   32768
#define DIN    1024
#define DH     2048
#define DOUT   1024
#define NEXP   8

typedef unsigned short u16;
typedef __bf16 bf16x8 __attribute__((ext_vector_type(8)));
typedef float  f32x4  __attribute__((ext_vector_type(4)));
typedef const __attribute__((address_space(1))) void gvoid_t;
typedef __attribute__((address_space(3))) void svoid_t;

__device__ __forceinline__ u16 f2bf(float f) {
  union { float f; uint32_t u; } v; v.f = f;
  return (u16)((v.u + 0x7FFFu + ((v.u >> 16) & 1u)) >> 16);  // RNE, no NaN in data
}

// ---------------- router: logits, softmax, argmax (no atomics) ----------------
__global__ __launch_bounds__(256) void k_router(
    const float* __restrict__ x, const float* __restrict__ Wr,
    const float* __restrict__ br, float* __restrict__ probs,
    int* __restrict__ routes)
{
  __shared__ float wr_s[NEXP * DIN];  // transposed Wr: [e][k]
  int tid = threadIdx.x;
  for (int idx = tid; idx < DIN * NEXP / 4; idx += 256) {
    float4 v = ((const float4*)Wr)[idx];
    int k = idx >> 1, r = (idx & 1) * 4;
    wr_s[(r + 0) * DIN + k] = v.x;
    wr_s[(r + 1) * DIN + k] = v.y;
    wr_s[(r + 2) * DIN + k] = v.z;
    wr_s[(r + 3) * DIN + k] = v.w;
  }
  __syncthreads();
  int lane = tid & 63, wv = tid >> 6;
  int t = blockIdx.x * 4 + wv;
  const float* xr = x + (size_t)t * DIN;
  float acc[NEXP];
  #pragma unroll
  for (int e = 0; e < NEXP; ++e) acc[e] = 0.f;
  #pragma unroll
  for (int i = 0; i < 4; ++i) {
    int k = i * 256 + lane * 4;
    float4 xv = *(const float4*)(xr + k);
    #pragma unroll
    for (int e = 0; e < NEXP; ++e) {
      float4 w4 = *(const float4*)(wr_s + e * DIN + k);
      acc[e] += xv.x * w4.x + xv.y * w4.y + xv.z * w4.z + xv.w * w4.w;
    }
  }
  #pragma unroll
  for (int off = 32; off >= 1; off >>= 1) {
    #pragma unroll
    for (int e = 0; e < NEXP; ++e) acc[e] += __shfl_xor(acc[e], off, 64);
  }
  if (lane == 0) {
    float l[NEXP], m = -1e30f;
    #pragma unroll
    for (int e = 0; e < NEXP; ++e) { l[e] = acc[e] + br[e]; m = fmaxf(m, l[e]); }
    float p[NEXP], s = 0.f;
    #pragma unroll
    for (int e = 0; e < NEXP; ++e) { p[e] = expf(l[e] - m); s += p[e]; }
    float inv = 1.f / s;
    int am = 0; float best = l[0];
    #pragma unroll
    for (int e = 1; e < NEXP; ++e) if (l[e] > best) { best = l[e]; am = e; }
    #pragma unroll
    for (int e = 0; e < NEXP; ++e) probs[(size_t)t * NEXP + e] = p[e] * inv;
    routes[t] = am;
  }
}

// ---------------- ballot-based counting: 8 atomics per wave ----------------
__global__ __launch_bounds__(256) void k_count(
    const int* __restrict__ routes, int* __restrict__ aux)
{
  int t = blockIdx.x * 256 + threadIdx.x;
  int e = routes[t];
  int lane = threadIdx.x & 63;
  #pragma unroll
  for (int ee = 0; ee < NEXP; ++ee) {
    unsigned long long m = __ballot(e == ee);
    if (lane == 0 && m) atomicAdd(&aux[ee], (int)__popcll(m));
  }
}

// ---------------- prefix + tile map (1 thread) ----------------
__global__ void k_prefix(int* __restrict__ aux, float* __restrict__ counts_out)
{
  if (threadIdx.x == 0) {
    int off = 0, nt = 0;
    for (int e = 0; e < NEXP; ++e) {
      int c = aux[e];
      counts_out[e] = (float)c;
      aux[24 + e] = off;
      int tiles = (c + 127) >> 7;
      for (int tt = 0; tt < tiles; ++tt) {
        aux[128 + nt] = e;
        aux[512 + nt] = off + tt * 128;
        aux[896 + nt] = off + c;
        ++nt;
      }
      off += c;
    }
    aux[16] = nt;
  }
}

// ---------------- ballot-prefix slot assignment: 8 atomics per wave ----------------
__global__ __launch_bounds__(256) void k_assign(
    const int* __restrict__ routes, int* __restrict__ aux,
    int* __restrict__ pos_of_tok, int* __restrict__ tok_of_pos)
{
  int t = blockIdx.x * 256 + threadIdx.x;
  int e = routes[t];
  int lane = threadIdx.x & 63;
  int p = 0;
  #pragma unroll
  for (int ee = 0; ee < NEXP; ++ee) {
    unsigned long long m = __ballot(e == ee);
    int base = 0;
    if (lane == 0 && m) base = atomicAdd(&aux[8 + ee], (int)__popcll(m));
    base = __shfl(base, 0, 64);
    if (e == ee)
      p = aux[24 + ee] + base + (int)__popcll(m & ((1ull << lane) - 1ull));
  }
  pos_of_tok[t] = p;
  tok_of_pos[p] = t;
}

// ---------------- gather x into sorted order, fp32 -> bf16 ----------------
__global__ __launch_bounds__(256) void k_permute(
    const float* __restrict__ x, const int* __restrict__ pos_of_tok,
    u16* __restrict__ xs)
{
  int t = blockIdx.x * 2 + (threadIdx.x >> 7);
  int j = threadIdx.x & 127;
  int p = pos_of_tok[t];
  const float4* src = (const float4*)(x + (size_t)t * DIN);
  u16* dst = xs + (size_t)p * DIN;
  #pragma unroll
  for (int h = 0; h < 2; ++h) {
    float4 v = src[h * 128 + j];
    ushort4 o;
    o.x = f2bf(v.x); o.y = f2bf(v.y); o.z = f2bf(v.z); o.w = f2bf(v.w);
    *(ushort4*)(dst + (h * 128 + j) * 4) = o;
  }
}

// ---------------- weight transpose+convert: [E][K][Nn] f32 -> [E][Nn][K] bf16 ----------------
__global__ __launch_bounds__(256) void k_transpose(
    const float* __restrict__ src, u16* __restrict__ dst, int K, int Nn)
{
  __shared__ float tile[64][65];
  int e = blockIdx.z;
  int k0 = blockIdx.x * 64, n0 = blockIdx.y * 64;
  const float* s = src + ((size_t)e * K + k0) * Nn + n0;
  int r = threadIdx.x >> 6, c = threadIdx.x & 63;
  #pragma unroll
  for (int i = 0; i < 16; ++i)
    tile[r + i * 4][c] = s[(size_t)(r + i * 4) * Nn + c];
  __syncthreads();
  u16* d = dst + ((size_t)e * Nn + n0) * K + k0;
  #pragma unroll
  for (int i = 0; i < 16; ++i) {
    int nr = r + i * 4;
    d[(size_t)nr * K + c] = f2bf(tile[c][nr]);
  }
}

// ---------------- grouped GEMM, m97 geometry: 128x128 tile, BK=64, 4 waves (2x2),
// per-wave 64x64 out (4x4 frags, 64 acc regs). Single-buffered 2-barrier loop.
// MODE 0: H = relu(A@B^T + bias) -> bf16   MODE 1: out[tok] = A@B^T + bias -> f32 scatter
template<int MODE>
__global__ __launch_bounds__(256, 3) void k_gemm(
    const u16* __restrict__ A, const u16* __restrict__ Bt,
    const float* __restrict__ bias, u16* __restrict__ Hout,
    float* __restrict__ Yout, const int* __restrict__ tok_of_pos,
    const int* __restrict__ aux, int K, int Nn)
{
  int bx = blockIdx.x;
  if (bx >= aux[16]) return;
  int e  = aux[128 + bx];
  int r0 = aux[512 + bx];
  int r1 = aux[896 + bx];
  int bn0 = blockIdx.y * 128;

  __shared__ __align__(16) u16 As[128 * 64];   // [row][k], 128B rows, slot-swizzled
  __shared__ __align__(16) u16 Bs[128 * 64];

  int tid = threadIdx.x;
  int lane = tid & 63, wv = tid >> 6;
  int wr = wv >> 1, wc = wv & 1;
  const u16* Be = Bt + (size_t)e * Nn * K;

  auto stage = [&](int kt) {
    int k0 = kt * 64;
    #pragma unroll
    for (int r = 0; r < 4; ++r) {              // A: 16 KB
      int L = (r * 256 + tid) * 16;
      int row = L >> 7;
      int sl = ((L >> 4) & 7) ^ (row & 7);     // pre-swizzle the global source (G21)
      int grow = r0 + row; grow = grow < NTOK ? grow : NTOK - 1;
      __builtin_amdgcn_global_load_lds(
          (gvoid_t*)((const char*)(A + (size_t)grow * K + k0) + sl * 16),
          (svoid_t*)((char*)As + L), 16, 0, 0);
    }
    #pragma unroll
    for (int r = 0; r < 4; ++r) {              // B: 16 KB
      int L = (r * 256 + tid) * 16;
      int row = L >> 7;
      int sl = ((L >> 4) & 7) ^ (row & 7);
      __builtin_amdgcn_global_load_lds(
          (gvoid_t*)((const char*)(Be + (size_t)(bn0 + row) * K + k0) + sl * 16),
          (svoid_t*)((char*)Bs + L), 16, 0, 0);
    }
  };

  f32x4 acc[4][4];
  #pragma unroll
  for (int i = 0; i < 4; ++i)
    #pragma unroll
    for (int j = 0; j < 4; ++j)
      acc[i][j] = (f32x4){0.f, 0.f, 0.f, 0.f};

  int KT = K >> 6;
  stage(0);
  for (int kt = 0; kt < KT; ++kt) {
    __syncthreads();
    const char* As_c = (const char*)As;
    const char* Bs_c = (const char*)Bs;
    #pragma unroll
    for (int kk = 0; kk < 2; ++kk) {
      int sw = ((kk * 4 + (lane >> 4)) ^ (lane & 7)) << 4;   // swizzled 16B slot
      bf16x8 a[4], b[4];
      #pragma unroll
      for (int f = 0; f < 4; ++f)
        a[f] = *(const bf16x8*)(As_c + (wr * 64 + f * 16 + (lane & 15)) * 128 + sw);
      #pragma unroll
      for (int f = 0; f < 4; ++f)
        b[f] = *(const bf16x8*)(Bs_c + (wc * 64 + f * 16 + (lane & 15)) * 128 + sw);
      #pragma unroll
      for (int i = 0; i < 4; ++i)
        #pragma unroll
        for (int j = 0; j < 4; ++j)
          acc[i][j] = __builtin_amdgcn_mfma_f32_16x16x32_bf16(a[i], b[j], acc[i][j], 0, 0, 0);
    }
    __syncthreads();
    if (kt + 1 < KT) stage(kt + 1);
  }

  const float* be = bias + (size_t)e * Nn;
  float bv[4];
  #pragma unroll
  for (int j = 0; j < 4; ++j) bv[j] = be[bn0 + wc * 64 + j * 16 + (lane & 15)];
  #pragma unroll
  for (int i = 0; i < 4; ++i) {
    #pragma unroll
    for (int q = 0; q < 4; ++q) {
      int r = r0 + wr * 64 + i * 16 + (lane >> 4) * 4 + q;  // C/D: col=lane&15, row=(lane>>4)*4+q [m89]
      if (r < r1) {
        if (MODE == 0) {
          u16* dst = Hout + (size_t)r * Nn + bn0 + wc * 64 + (lane & 15);
          #pragma unroll
          for (int j = 0; j < 4; ++j)
            dst[j * 16] = f2bf(fmaxf(acc[i][j][q] + bv[j], 0.f));
        } else {
          int tok = tok_of_pos[r];
          float* dst = Yout + (size_t)tok * Nn + bn0 + wc * 64 + (lane & 15);
          #pragma unroll
          for (int j = 0; j < 4; ++j)
            dst[j * 16] = acc[i][j][q] + bv[j];
        }
      }
    }
  }
}

extern "C" void kernel_launch(void* const* d_in, const int* in_sizes, int n_in,
                              void* d_out, int out_size, void* d_ws, size_t ws_size,
                              hipStream_t stream)
{
  const float* x  = (const float*)d_in[0];
  const float* Wr = (const float*)d_in[1];
  const float* br = (const float*)d_in[2];
  const float* W1 = (const float*)d_in[3];
  const float* b1 = (const float*)d_in[4];
  const float* W2 = (const float*)d_in[5];
  const float* b2 = (const float*)d_in[6];

  float* out    = (float*)d_out;                       // [N][1024]
  float* probs  = out + (size_t)NTOK * DOUT;           // [N][8]
  float* counts = probs + (size_t)NTOK * NEXP;         // [8]

  char* ws = (char*)d_ws;
  u16* xs          = (u16*)(ws);
  u16* h           = (u16*)(ws + 67108864);
  u16* W1t         = (u16*)(ws + 201326592);
  u16* W2t         = (u16*)(ws + 234881024);
  int* aux         = (int*)(ws + 268435456);
  int* routes      = (int*)(ws + 268451840);
  int* pos_of_tok  = (int*)(ws + 268582912);
  int* tok_of_pos  = (int*)(ws + 268713984);

  (void)hipMemsetAsync(aux, 0, 16384, stream);
  k_router<<<NTOK / 4, 256, 0, stream>>>(x, Wr, br, probs, routes);
  k_count<<<NTOK / 256, 256, 0, stream>>>(routes, aux);
  k_transpose<<<dim3(DIN / 64, DH / 64, NEXP), 256, 0, stream>>>(W1, W1t, DIN, DH);
  k_transpose<<<dim3(DH / 64, DOUT / 64, NEXP), 256, 0, stream>>>(W2, W2t, DH, DOUT);
  k_prefix<<<1, 64, 0, stream>>>(aux, counts);
  k_assign<<<NTOK / 256, 256, 0, stream>>>(routes, aux, pos_of_tok, tok_of_pos);
  k_permute<<<NTOK / 2, 256, 0, stream>>>(x, pos_of_tok, xs);
  k_gemm<0><<<dim3(264, DH / 128), 256, 0, stream>>>(xs, W1t, b1, h, nullptr, nullptr, aux, DIN, DH);
  k_gemm<1><<<dim3(264, DOUT / 128), 256, 0, stream>>>(h, W2t, b2, nullptr, out, tok_of_pos, aux, DH, DOUT);
}

// Round 5
// 553.634 us; speedup vs baseline: 2.6881x; 1.1516x over previous
//
#include <hip/hip_runtime.h>
#include <stdint.h>

// MoE top-1: router (fp32) + grouped bf16-MFMA GEMM over expert-sorted tokens.
// R5: + XCD-chunked by-fastest tile swizzle in k_gemm (T1; kills 16x A-panel
//     re-fetch: FETCH 621MB -> target <400MB) + launch_bounds(256,4) (4 blk/CU).
// ws layout (bytes):
//   0          : xs   bf16 [N][1024]  expert-sorted x            (64 MB)
//   67108864   : h    bf16 [N][2048]  relu(x@W1+b1), sorted      (128 MB)
//   201326592  : W1t  bf16 [8][2048][1024]                       (32 MB)
//   234881024  : W2t  bf16 [8][1024][2048]                       (32 MB)
//   268435456  : aux  int[4096]: cnt[0..7] cursor[8..15] ntiles[16] offs[24..31]
//                tile_e[128..] tile_r0[512..] tile_r1[896..]     (16 KB, memset 0)
//   268451840  : routes     int[N]
//   268582912  : pos_of_tok int[N]
//   268713984  : tok_of_pos int[N]   -> total 268,845,056 B

#define NTOK   32768
#define DIN    1024
#define DH     2048
#define DOUT   1024
#define NEXP   8

typedef unsigned short u16;
typedef __bf16 bf16x8 __attribute__((ext_vector_type(8)));
typedef float  f32x4  __attribute__((ext_vector_type(4)));
typedef const __attribute__((address_space(1))) void gvoid_t;
typedef __attribute__((address_space(3))) void svoid_t;

__device__ __forceinline__ u16 f2bf(float f) {
  union { float f; uint32_t u; } v; v.f = f;
  return (u16)((v.u + 0x7FFFu + ((v.u >> 16) & 1u)) >> 16);  // RNE, no NaN in data
}

// ---------------- router: logits, softmax, argmax (no atomics) ----------------
__global__ __launch_bounds__(256) void k_router(
    const float* __restrict__ x, const float* __restrict__ Wr,
    const float* __restrict__ br, float* __restrict__ probs,
    int* __restrict__ routes)
{
  __shared__ float wr_s[NEXP * DIN];  // transposed Wr: [e][k]
  int tid = threadIdx.x;
  for (int idx = tid; idx < DIN * NEXP / 4; idx += 256) {
    float4 v = ((const float4*)Wr)[idx];
    int k = idx >> 1, r = (idx & 1) * 4;
    wr_s[(r + 0) * DIN + k] = v.x;
    wr_s[(r + 1) * DIN + k] = v.y;
    wr_s[(r + 2) * DIN + k] = v.z;
    wr_s[(r + 3) * DIN + k] = v.w;
  }
  __syncthreads();
  int lane = tid & 63, wv = tid >> 6;
  int t = blockIdx.x * 4 + wv;
  const float* xr = x + (size_t)t * DIN;
  float acc[NEXP];
  #pragma unroll
  for (int e = 0; e < NEXP; ++e) acc[e] = 0.f;
  #pragma unroll
  for (int i = 0; i < 4; ++i) {
    int k = i * 256 + lane * 4;
    float4 xv = *(const float4*)(xr + k);
    #pragma unroll
    for (int e = 0; e < NEXP; ++e) {
      float4 w4 = *(const float4*)(wr_s + e * DIN + k);
      acc[e] += xv.x * w4.x + xv.y * w4.y + xv.z * w4.z + xv.w * w4.w;
    }
  }
  #pragma unroll
  for (int off = 32; off >= 1; off >>= 1) {
    #pragma unroll
    for (int e = 0; e < NEXP; ++e) acc[e] += __shfl_xor(acc[e], off, 64);
  }
  if (lane == 0) {
    float l[NEXP], m = -1e30f;
    #pragma unroll
    for (int e = 0; e < NEXP; ++e) { l[e] = acc[e] + br[e]; m = fmaxf(m, l[e]); }
    float p[NEXP], s = 0.f;
    #pragma unroll
    for (int e = 0; e < NEXP; ++e) { p[e] = expf(l[e] - m); s += p[e]; }
    float inv = 1.f / s;
    int am = 0; float best = l[0];
    #pragma unroll
    for (int e = 1; e < NEXP; ++e) if (l[e] > best) { best = l[e]; am = e; }
    #pragma unroll
    for (int e = 0; e < NEXP; ++e) probs[(size_t)t * NEXP + e] = p[e] * inv;
    routes[t] = am;
  }
}

// ---------------- ballot-based counting: 8 atomics per wave ----------------
__global__ __launch_bounds__(256) void k_count(
    const int* __restrict__ routes, int* __restrict__ aux)
{
  int t = blockIdx.x * 256 + threadIdx.x;
  int e = routes[t];
  int lane = threadIdx.x & 63;
  #pragma unroll
  for (int ee = 0; ee < NEXP; ++ee) {
    unsigned long long m = __ballot(e == ee);
    if (lane == 0 && m) atomicAdd(&aux[ee], (int)__popcll(m));
  }
}

// ---------------- prefix + tile map (1 thread) ----------------
__global__ void k_prefix(int* __restrict__ aux, float* __restrict__ counts_out)
{
  if (threadIdx.x == 0) {
    int off = 0, nt = 0;
    for (int e = 0; e < NEXP; ++e) {
      int c = aux[e];
      counts_out[e] = (float)c;
      aux[24 + e] = off;
      int tiles = (c + 127) >> 7;
      for (int tt = 0; tt < tiles; ++tt) {
        aux[128 + nt] = e;
        aux[512 + nt] = off + tt * 128;
        aux[896 + nt] = off + c;
        ++nt;
      }
      off += c;
    }
    aux[16] = nt;
  }
}

// ---------------- ballot-prefix slot assignment: 8 atomics per wave ----------------
__global__ __launch_bounds__(256) void k_assign(
    const int* __restrict__ routes, int* __restrict__ aux,
    int* __restrict__ pos_of_tok, int* __restrict__ tok_of_pos)
{
  int t = blockIdx.x * 256 + threadIdx.x;
  int e = routes[t];
  int lane = threadIdx.x & 63;
  int p = 0;
  #pragma unroll
  for (int ee = 0; ee < NEXP; ++ee) {
    unsigned long long m = __ballot(e == ee);
    int base = 0;
    if (lane == 0 && m) base = atomicAdd(&aux[8 + ee], (int)__popcll(m));
    base = __shfl(base, 0, 64);
    if (e == ee)
      p = aux[24 + ee] + base + (int)__popcll(m & ((1ull << lane) - 1ull));
  }
  pos_of_tok[t] = p;
  tok_of_pos[p] = t;
}

// ---------------- gather x into sorted order, fp32 -> bf16 ----------------
__global__ __launch_bounds__(256) void k_permute(
    const float* __restrict__ x, const int* __restrict__ pos_of_tok,
    u16* __restrict__ xs)
{
  int t = blockIdx.x * 2 + (threadIdx.x >> 7);
  int j = threadIdx.x & 127;
  int p = pos_of_tok[t];
  const float4* src = (const float4*)(x + (size_t)t * DIN);
  u16* dst = xs + (size_t)p * DIN;
  #pragma unroll
  for (int h = 0; h < 2; ++h) {
    float4 v = src[h * 128 + j];
    ushort4 o;
    o.x = f2bf(v.x); o.y = f2bf(v.y); o.z = f2bf(v.z); o.w = f2bf(v.w);
    *(ushort4*)(dst + (h * 128 + j) * 4) = o;
  }
}

// ---------------- weight transpose+convert: [E][K][Nn] f32 -> [E][Nn][K] bf16 ----------------
__global__ __launch_bounds__(256) void k_transpose(
    const float* __restrict__ src, u16* __restrict__ dst, int K, int Nn)
{
  __shared__ float tile[64][65];
  int e = blockIdx.z;
  int k0 = blockIdx.x * 64, n0 = blockIdx.y * 64;
  const float* s = src + ((size_t)e * K + k0) * Nn + n0;
  int r = threadIdx.x >> 6, c = threadIdx.x & 63;
  #pragma unroll
  for (int i = 0; i < 16; ++i)
    tile[r + i * 4][c] = s[(size_t)(r + i * 4) * Nn + c];
  __syncthreads();
  u16* d = dst + ((size_t)e * Nn + n0) * K + k0;
  #pragma unroll
  for (int i = 0; i < 16; ++i) {
    int nr = r + i * 4;
    d[(size_t)nr * K + c] = f2bf(tile[c][nr]);
  }
}

// ---------------- grouped GEMM, m97 geometry: 128x128 tile, BK=64, 4 waves (2x2),
// per-wave 64x64 out (4x4 frags, 64 acc regs). Single-buffered 2-barrier loop.
// 1D grid with XCD-chunked, N-fastest tile order: each XCD owns a contiguous
// chunk of A-panels; the Nn/128 N-tiles of one A-panel are consecutive on the
// same XCD -> A-panel fetched ~once per XCD into its L2 (T1).
// MODE 0: H = relu(A@B^T + bias) -> bf16   MODE 1: out[tok] = A@B^T + bias -> f32 scatter
template<int MODE>
__global__ __launch_bounds__(256, 4) void k_gemm(
    const u16* __restrict__ A, const u16* __restrict__ Bt,
    const float* __restrict__ bias, u16* __restrict__ Hout,
    float* __restrict__ Yout, const int* __restrict__ tok_of_pos,
    const int* __restrict__ aux, int K, int Nn, int nbyl)
{
  // XCD-chunked swizzle (hw: consecutive blockIdx round-robin across 8 XCDs)
  int nwg = gridDim.x;                 // 264 << nbyl, divisible by 8
  int bid = blockIdx.x;
  int wg  = (bid & 7) * (nwg >> 3) + (bid >> 3);
  int by  = wg & ((1 << nbyl) - 1);    // N-fastest within the XCD chunk
  int bx  = wg >> nbyl;
  if (bx >= aux[16]) return;
  int e  = aux[128 + bx];
  int r0 = aux[512 + bx];
  int r1 = aux[896 + bx];
  int bn0 = by << 7;

  __shared__ __align__(16) u16 As[128 * 64];   // [row][k], 128B rows, slot-swizzled
  __shared__ __align__(16) u16 Bs[128 * 64];

  int tid = threadIdx.x;
  int lane = tid & 63, wv = tid >> 6;
  int wr = wv >> 1, wc = wv & 1;
  const u16* Be = Bt + (size_t)e * Nn * K;

  auto stage = [&](int kt) {
    int k0 = kt * 64;
    #pragma unroll
    for (int r = 0; r < 4; ++r) {              // A: 16 KB
      int L = (r * 256 + tid) * 16;
      int row = L >> 7;
      int sl = ((L >> 4) & 7) ^ (row & 7);     // pre-swizzle the global source (G21)
      int grow = r0 + row; grow = grow < NTOK ? grow : NTOK - 1;
      __builtin_amdgcn_global_load_lds(
          (gvoid_t*)((const char*)(A + (size_t)grow * K + k0) + sl * 16),
          (svoid_t*)((char*)As + L), 16, 0, 0);
    }
    #pragma unroll
    for (int r = 0; r < 4; ++r) {              // B: 16 KB
      int L = (r * 256 + tid) * 16;
      int row = L >> 7;
      int sl = ((L >> 4) & 7) ^ (row & 7);
      __builtin_amdgcn_global_load_lds(
          (gvoid_t*)((const char*)(Be + (size_t)(bn0 + row) * K + k0) + sl * 16),
          (svoid_t*)((char*)Bs + L), 16, 0, 0);
    }
  };

  f32x4 acc[4][4];
  #pragma unroll
  for (int i = 0; i < 4; ++i)
    #pragma unroll
    for (int j = 0; j < 4; ++j)
      acc[i][j] = (f32x4){0.f, 0.f, 0.f, 0.f};

  int KT = K >> 6;
  stage(0);
  for (int kt = 0; kt < KT; ++kt) {
    __syncthreads();
    const char* As_c = (const char*)As;
    const char* Bs_c = (const char*)Bs;
    #pragma unroll
    for (int kk = 0; kk < 2; ++kk) {
      int sw = ((kk * 4 + (lane >> 4)) ^ (lane & 7)) << 4;   // swizzled 16B slot
      bf16x8 a[4], b[4];
      #pragma unroll
      for (int f = 0; f < 4; ++f)
        a[f] = *(const bf16x8*)(As_c + (wr * 64 + f * 16 + (lane & 15)) * 128 + sw);
      #pragma unroll
      for (int f = 0; f < 4; ++f)
        b[f] = *(const bf16x8*)(Bs_c + (wc * 64 + f * 16 + (lane & 15)) * 128 + sw);
      #pragma unroll
      for (int i = 0; i < 4; ++i)
        #pragma unroll
        for (int j = 0; j < 4; ++j)
          acc[i][j] = __builtin_amdgcn_mfma_f32_16x16x32_bf16(a[i], b[j], acc[i][j], 0, 0, 0);
    }
    __syncthreads();
    if (kt + 1 < KT) stage(kt + 1);
  }

  const float* be = bias + (size_t)e * Nn;
  float bv[4];
  #pragma unroll
  for (int j = 0; j < 4; ++j) bv[j] = be[bn0 + wc * 64 + j * 16 + (lane & 15)];
  #pragma unroll
  for (int i = 0; i < 4; ++i) {
    #pragma unroll
    for (int q = 0; q < 4; ++q) {
      int r = r0 + wr * 64 + i * 16 + (lane >> 4) * 4 + q;  // C/D: col=lane&15, row=(lane>>4)*4+q [m89]
      if (r < r1) {
        if (MODE == 0) {
          u16* dst = Hout + (size_t)r * Nn + bn0 + wc * 64 + (lane & 15);
          #pragma unroll
          for (int j = 0; j < 4; ++j)
            dst[j * 16] = f2bf(fmaxf(acc[i][j][q] + bv[j], 0.f));
        } else {
          int tok = tok_of_pos[r];
          float* dst = Yout + (size_t)tok * Nn + bn0 + wc * 64 + (lane & 15);
          #pragma unroll
          for (int j = 0; j < 4; ++j)
            dst[j * 16] = acc[i][j][q] + bv[j];
        }
      }
    }
  }
}

extern "C" void kernel_launch(void* const* d_in, const int* in_sizes, int n_in,
                              void* d_out, int out_size, void* d_ws, size_t ws_size,
                              hipStream_t stream)
{
  const float* x  = (const float*)d_in[0];
  const float* Wr = (const float*)d_in[1];
  const float* br = (const float*)d_in[2];
  const float* W1 = (const float*)d_in[3];
  const float* b1 = (const float*)d_in[4];
  const float* W2 = (const float*)d_in[5];
  const float* b2 = (const float*)d_in[6];

  float* out    = (float*)d_out;                       // [N][1024]
  float* probs  = out + (size_t)NTOK * DOUT;           // [N][8]
  float* counts = probs + (size_t)NTOK * NEXP;         // [8]

  char* ws = (char*)d_ws;
  u16* xs          = (u16*)(ws);
  u16* h           = (u16*)(ws + 67108864);
  u16* W1t         = (u16*)(ws + 201326592);
  u16* W2t         = (u16*)(ws + 234881024);
  int* aux         = (int*)(ws + 268435456);
  int* routes      = (int*)(ws + 268451840);
  int* pos_of_tok  = (int*)(ws + 268582912);
  int* tok_of_pos  = (int*)(ws + 268713984);

  (void)hipMemsetAsync(aux, 0, 16384, stream);
  k_router<<<NTOK / 4, 256, 0, stream>>>(x, Wr, br, probs, routes);
  k_count<<<NTOK / 256, 256, 0, stream>>>(routes, aux);
  k_transpose<<<dim3(DIN / 64, DH / 64, NEXP), 256, 0, stream>>>(W1, W1t, DIN, DH);
  k_transpose<<<dim3(DH / 64, DOUT / 64, NEXP), 256, 0, stream>>>(W2, W2t, DH, DOUT);
  k_prefix<<<1, 64, 0, stream>>>(aux, counts);
  k_assign<<<NTOK / 256, 256, 0, stream>>>(routes, aux, pos_of_tok, tok_of_pos);
  k_permute<<<NTOK / 2, 256, 0, stream>>>(x, pos_of_tok, xs);
  k_gemm<0><<<264 * 16, 256, 0, stream>>>(xs, W1t, b1, h, nullptr, nullptr, aux, DIN, DH, 4);
  k_gemm<1><<<264 * 8, 256, 0, stream>>>(h, W2t, b2, nullptr, out, tok_of_pos, aux, DH, DOUT, 3);
}

// Round 6
// 526.193 us; speedup vs baseline: 2.8283x; 1.0522x over previous
//
#include <hip/hip_runtime.h>
#include <stdint.h>

// MoE top-1: router (fp32) + grouped bf16-MFMA GEMM over expert-sorted tokens.
// R6: tail fusion — router also emits bf16(x) (kills k_permute; GEMM1 gathers
//     rows via tok_of_pos with per-lane global_load_lds sources), parallel
//     k_prefix, merged transpose launch. GEMM structure unchanged from R5.
// ws layout (bytes):
//   0          : xb   bf16 [N][1024]  bf16(x), TOKEN order       (64 MB)
//   67108864   : h    bf16 [N][2048]  relu(x@W1+b1), SORTED      (128 MB)
//   201326592  : W1t  bf16 [8][2048][1024]                       (32 MB)
//   234881024  : W2t  bf16 [8][1024][2048]                       (32 MB)
//   268435456  : aux  int[4096]: cnt[0..7] cursor[8..15] ntiles[16] offs[24..31]
//                tile_e[128..] tile_r0[512..] tile_r1[896..]     (16 KB, memset 0)
//   268451840  : routes     int[N]
//   268582912  : pos_of_tok int[N]
//   268713984  : tok_of_pos int[N]   -> total 268,845,056 B

#define NTOK   32768
#define DIN    1024
#define DH     2048
#define DOUT   1024
#define NEXP   8

typedef unsigned short u16;
typedef __bf16 bf16x8 __attribute__((ext_vector_type(8)));
typedef float  f32x4  __attribute__((ext_vector_type(4)));
typedef const __attribute__((address_space(1))) void gvoid_t;
typedef __attribute__((address_space(3))) void svoid_t;

__device__ __forceinline__ u16 f2bf(float f) {
  union { float f; uint32_t u; } v; v.f = f;
  return (u16)((v.u + 0x7FFFu + ((v.u >> 16) & 1u)) >> 16);  // RNE, no NaN in data
}

// ---------------- router: logits, softmax, argmax + bf16(x) emit ----------------
__global__ __launch_bounds__(256) void k_router(
    const float* __restrict__ x, const float* __restrict__ Wr,
    const float* __restrict__ br, float* __restrict__ probs,
    int* __restrict__ routes, u16* __restrict__ xb)
{
  __shared__ float wr_s[NEXP * DIN];  // transposed Wr: [e][k]
  int tid = threadIdx.x;
  for (int idx = tid; idx < DIN * NEXP / 4; idx += 256) {
    float4 v = ((const float4*)Wr)[idx];
    int k = idx >> 1, r = (idx & 1) * 4;
    wr_s[(r + 0) * DIN + k] = v.x;
    wr_s[(r + 1) * DIN + k] = v.y;
    wr_s[(r + 2) * DIN + k] = v.z;
    wr_s[(r + 3) * DIN + k] = v.w;
  }
  __syncthreads();
  int lane = tid & 63, wv = tid >> 6;
  int t = blockIdx.x * 4 + wv;
  const float* xr = x + (size_t)t * DIN;
  u16* xbrow = xb + (size_t)t * DIN;
  float acc[NEXP];
  #pragma unroll
  for (int e = 0; e < NEXP; ++e) acc[e] = 0.f;
  #pragma unroll
  for (int i = 0; i < 4; ++i) {
    int k = i * 256 + lane * 4;
    float4 xv = *(const float4*)(xr + k);
    ushort4 o;
    o.x = f2bf(xv.x); o.y = f2bf(xv.y); o.z = f2bf(xv.z); o.w = f2bf(xv.w);
    *(ushort4*)(xbrow + k) = o;              // bf16 copy, token order
    #pragma unroll
    for (int e = 0; e < NEXP; ++e) {
      float4 w4 = *(const float4*)(wr_s + e * DIN + k);
      acc[e] += xv.x * w4.x + xv.y * w4.y + xv.z * w4.z + xv.w * w4.w;
    }
  }
  #pragma unroll
  for (int off = 32; off >= 1; off >>= 1) {
    #pragma unroll
    for (int e = 0; e < NEXP; ++e) acc[e] += __shfl_xor(acc[e], off, 64);
  }
  if (lane == 0) {
    float l[NEXP], m = -1e30f;
    #pragma unroll
    for (int e = 0; e < NEXP; ++e) { l[e] = acc[e] + br[e]; m = fmaxf(m, l[e]); }
    float p[NEXP], s = 0.f;
    #pragma unroll
    for (int e = 0; e < NEXP; ++e) { p[e] = expf(l[e] - m); s += p[e]; }
    float inv = 1.f / s;
    int am = 0; float best = l[0];
    #pragma unroll
    for (int e = 1; e < NEXP; ++e) if (l[e] > best) { best = l[e]; am = e; }
    #pragma unroll
    for (int e = 0; e < NEXP; ++e) probs[(size_t)t * NEXP + e] = p[e] * inv;
    routes[t] = am;
  }
}

// ---------------- ballot-based counting: 8 atomics per wave ----------------
__global__ __launch_bounds__(256) void k_count(
    const int* __restrict__ routes, int* __restrict__ aux)
{
  int t = blockIdx.x * 256 + threadIdx.x;
  int e = routes[t];
  int lane = threadIdx.x & 63;
  #pragma unroll
  for (int ee = 0; ee < NEXP; ++ee) {
    unsigned long long m = __ballot(e == ee);
    if (lane == 0 && m) atomicAdd(&aux[ee], (int)__popcll(m));
  }
}

// ---------------- prefix + tile map (1 block, lane-parallel fill) ----------------
__global__ __launch_bounds__(256) void k_prefix(int* __restrict__ aux, float* __restrict__ counts_out)
{
  __shared__ int s_off[NEXP], s_cnt[NEXP], s_tb[NEXP], s_nt;
  int tid = threadIdx.x;
  if (tid == 0) {
    int off = 0, tb = 0;
    for (int e = 0; e < NEXP; ++e) {
      int c = aux[e];
      counts_out[e] = (float)c;
      s_cnt[e] = c; s_off[e] = off; s_tb[e] = tb;
      aux[24 + e] = off;
      off += c; tb += (c + 127) >> 7;
    }
    s_nt = tb;
    aux[16] = tb;
  }
  __syncthreads();
  int nt = s_nt;
  for (int i = tid; i < nt; i += 256) {
    int e = 0;
    #pragma unroll
    for (int k = 1; k < NEXP; ++k) if (i >= s_tb[k]) e = k;
    int tt = i - s_tb[e];
    aux[128 + i] = e;
    aux[512 + i] = s_off[e] + tt * 128;
    aux[896 + i] = s_off[e] + s_cnt[e];
  }
}

// ---------------- ballot-prefix slot assignment: 8 atomics per wave ----------------
__global__ __launch_bounds__(256) void k_assign(
    const int* __restrict__ routes, int* __restrict__ aux,
    int* __restrict__ pos_of_tok, int* __restrict__ tok_of_pos)
{
  int t = blockIdx.x * 256 + threadIdx.x;
  int e = routes[t];
  int lane = threadIdx.x & 63;
  int p = 0;
  #pragma unroll
  for (int ee = 0; ee < NEXP; ++ee) {
    unsigned long long m = __ballot(e == ee);
    int base = 0;
    if (lane == 0 && m) base = atomicAdd(&aux[8 + ee], (int)__popcll(m));
    base = __shfl(base, 0, 64);
    if (e == ee)
      p = aux[24 + ee] + base + (int)__popcll(m & ((1ull << lane) - 1ull));
  }
  pos_of_tok[t] = p;
  tok_of_pos[p] = t;
}

// ---------------- merged weight transpose+convert: [E][K][Nn] f32 -> [E][Nn][K] bf16 ----------------
__global__ __launch_bounds__(256) void k_transpose(
    const float* __restrict__ W1, u16* __restrict__ W1t,
    const float* __restrict__ W2, u16* __restrict__ W2t)
{
  int z = blockIdx.z;
  const float* src; u16* dst; int K, Nn, e;
  if (z < NEXP) { src = W1; dst = W1t; K = DIN; Nn = DH;   e = z; }
  else          { src = W2; dst = W2t; K = DH;  Nn = DOUT; e = z - NEXP; }
  int k0 = blockIdx.x * 64, n0 = blockIdx.y * 64;
  if (k0 >= K || n0 >= Nn) return;
  __shared__ float tile[64][65];
  const float* s = src + ((size_t)e * K + k0) * Nn + n0;
  int r = threadIdx.x >> 6, c = threadIdx.x & 63;
  #pragma unroll
  for (int i = 0; i < 16; ++i)
    tile[r + i * 4][c] = s[(size_t)(r + i * 4) * Nn + c];
  __syncthreads();
  u16* d = dst + ((size_t)e * Nn + n0) * K + k0;
  #pragma unroll
  for (int i = 0; i < 16; ++i) {
    int nr = r + i * 4;
    d[(size_t)nr * K + c] = f2bf(tile[c][nr]);
  }
}

// ---------------- grouped GEMM, m97 geometry: 128x128 tile, BK=64, 4 waves (2x2),
// per-wave 64x64 out (4x4 frags, 64 acc regs). Single-buffered 2-barrier loop.
// XCD-chunked 1D grid, N-fastest within chunk (T1: A-panel L2 reuse, R5-verified
// FETCH 621->151MB). GATHER=1: A rows indirected through tok_of_pos (A is xb in
// token order); GATHER=0: A already sorted (h).
// MODE 0: H = relu(A@B^T + bias) -> bf16   MODE 1: out[tok] = A@B^T + bias -> f32 scatter
template<int MODE, int GATHER>
__global__ __launch_bounds__(256, 4) void k_gemm(
    const u16* __restrict__ A, const u16* __restrict__ Bt,
    const float* __restrict__ bias, u16* __restrict__ Hout,
    float* __restrict__ Yout, const int* __restrict__ tok_of_pos,
    const int* __restrict__ aux, int K, int Nn, int nbyl)
{
  int nwg = gridDim.x;                 // divisible by 8
  int bid = blockIdx.x;
  int wg  = (bid & 7) * (nwg >> 3) + (bid >> 3);
  int by  = wg & ((1 << nbyl) - 1);    // N-fastest within the XCD chunk
  int bx  = wg >> nbyl;
  if (bx >= aux[16]) return;
  int e  = aux[128 + bx];
  int r0 = aux[512 + bx];
  int r1 = aux[896 + bx];
  int bn0 = by << 7;

  __shared__ __align__(16) u16 As[128 * 64];   // [row][k], 128B rows, slot-swizzled
  __shared__ __align__(16) u16 Bs[128 * 64];

  int tid = threadIdx.x;
  int lane = tid & 63, wv = tid >> 6;
  int wr = wv >> 1, wc = wv & 1;
  const u16* Be = Bt + (size_t)e * Nn * K;

  // A-row ids this thread stages (row = r*32 + tid/8), gathered if needed
  int tk[4];
  #pragma unroll
  for (int r = 0; r < 4; ++r) {
    int gr = r0 + r * 32 + (tid >> 3);
    gr = gr < NTOK ? gr : NTOK - 1;
    tk[r] = GATHER ? tok_of_pos[gr] : gr;
  }

  auto stage = [&](int kt) {
    int k0 = kt * 64;
    #pragma unroll
    for (int r = 0; r < 4; ++r) {              // A: 16 KB
      int L = (r * 256 + tid) * 16;
      int sl = ((L >> 4) & 7) ^ ((L >> 7) & 7);   // pre-swizzle global source (G21)
      __builtin_amdgcn_global_load_lds(
          (gvoid_t*)((const char*)(A + (size_t)tk[r] * K + k0) + sl * 16),
          (svoid_t*)((char*)As + L), 16, 0, 0);
    }
    #pragma unroll
    for (int r = 0; r < 4; ++r) {              // B: 16 KB
      int L = (r * 256 + tid) * 16;
      int row = L >> 7;
      int sl = ((L >> 4) & 7) ^ (row & 7);
      __builtin_amdgcn_global_load_lds(
          (gvoid_t*)((const char*)(Be + (size_t)(bn0 + row) * K + k0) + sl * 16),
          (svoid_t*)((char*)Bs + L), 16, 0, 0);
    }
  };

  f32x4 acc[4][4];
  #pragma unroll
  for (int i = 0; i < 4; ++i)
    #pragma unroll
    for (int j = 0; j < 4; ++j)
      acc[i][j] = (f32x4){0.f, 0.f, 0.f, 0.f};

  int KT = K >> 6;
  stage(0);
  for (int kt = 0; kt < KT; ++kt) {
    __syncthreads();
    const char* As_c = (const char*)As;
    const char* Bs_c = (const char*)Bs;
    #pragma unroll
    for (int kk = 0; kk < 2; ++kk) {
      int sw = ((kk * 4 + (lane >> 4)) ^ (lane & 7)) << 4;   // swizzled 16B slot
      bf16x8 a[4], b[4];
      #pragma unroll
      for (int f = 0; f < 4; ++f)
        a[f] = *(const bf16x8*)(As_c + (wr * 64 + f * 16 + (lane & 15)) * 128 + sw);
      #pragma unroll
      for (int f = 0; f < 4; ++f)
        b[f] = *(const bf16x8*)(Bs_c + (wc * 64 + f * 16 + (lane & 15)) * 128 + sw);
      #pragma unroll
      for (int i = 0; i < 4; ++i)
        #pragma unroll
        for (int j = 0; j < 4; ++j)
          acc[i][j] = __builtin_amdgcn_mfma_f32_16x16x32_bf16(a[i], b[j], acc[i][j], 0, 0, 0);
    }
    __syncthreads();
    if (kt + 1 < KT) stage(kt + 1);
  }

  const float* be = bias + (size_t)e * Nn;
  float bv[4];
  #pragma unroll
  for (int j = 0; j < 4; ++j) bv[j] = be[bn0 + wc * 64 + j * 16 + (lane & 15)];
  #pragma unroll
  for (int i = 0; i < 4; ++i) {
    #pragma unroll
    for (int q = 0; q < 4; ++q) {
      int r = r0 + wr * 64 + i * 16 + (lane >> 4) * 4 + q;  // C/D: col=lane&15, row=(lane>>4)*4+q [m89]
      if (r < r1) {
        if (MODE == 0) {
          u16* dst = Hout + (size_t)r * Nn + bn0 + wc * 64 + (lane & 15);
          #pragma unroll
          for (int j = 0; j < 4; ++j)
            dst[j * 16] = f2bf(fmaxf(acc[i][j][q] + bv[j], 0.f));
        } else {
          int tok = tok_of_pos[r];
          float* dst = Yout + (size_t)tok * Nn + bn0 + wc * 64 + (lane & 15);
          #pragma unroll
          for (int j = 0; j < 4; ++j)
            dst[j * 16] = acc[i][j][q] + bv[j];
        }
      }
    }
  }
}

extern "C" void kernel_launch(void* const* d_in, const int* in_sizes, int n_in,
                              void* d_out, int out_size, void* d_ws, size_t ws_size,
                              hipStream_t stream)
{
  const float* x  = (const float*)d_in[0];
  const float* Wr = (const float*)d_in[1];
  const float* br = (const float*)d_in[2];
  const float* W1 = (const float*)d_in[3];
  const float* b1 = (const float*)d_in[4];
  const float* W2 = (const float*)d_in[5];
  const float* b2 = (const float*)d_in[6];

  float* out    = (float*)d_out;                       // [N][1024]
  float* probs  = out + (size_t)NTOK * DOUT;           // [N][8]
  float* counts = probs + (size_t)NTOK * NEXP;         // [8]

  char* ws = (char*)d_ws;
  u16* xb          = (u16*)(ws);
  u16* h           = (u16*)(ws + 67108864);
  u16* W1t         = (u16*)(ws + 201326592);
  u16* W2t         = (u16*)(ws + 234881024);
  int* aux         = (int*)(ws + 268435456);
  int* routes      = (int*)(ws + 268451840);
  int* pos_of_tok  = (int*)(ws + 268582912);
  int* tok_of_pos  = (int*)(ws + 268713984);

  (void)hipMemsetAsync(aux, 0, 16384, stream);
  k_router<<<NTOK / 4, 256, 0, stream>>>(x, Wr, br, probs, routes, xb);
  k_count<<<NTOK / 256, 256, 0, stream>>>(routes, aux);
  k_transpose<<<dim3(32, 32, 2 * NEXP), 256, 0, stream>>>(W1, W1t, W2, W2t);
  k_prefix<<<1, 256, 0, stream>>>(aux, counts);
  k_assign<<<NTOK / 256, 256, 0, stream>>>(routes, aux, pos_of_tok, tok_of_pos);
  k_gemm<0, 1><<<264 * 16, 256, 0, stream>>>(xb, W1t, b1, h, nullptr, tok_of_pos, aux, DIN, DH, 4);
  k_gemm<1, 0><<<264 * 8, 256, 0, stream>>>(h, W2t, b2, nullptr, out, tok_of_pos, aux, DH, DOUT, 3);
}